// Round 1
// baseline (1015.368 us; speedup 1.0000x reference)
//
#include <hip/hip_runtime.h>

#define T_ 4
#define B_ 16
#define C_ 512
#define N_ 256
#define TB_ 64

using u64 = unsigned long long;

// ---------------------------------------------------------------------------
// GEMM: Y[tb,o,n] = sum_c W[o,c] * X[tb,c,n]   (fp32 inputs, fp64 accumulate)
// X: [TB, C, N] fp32 (contiguous), W: [C, C] row-major, Y: [TB, C, N] fp64
// Block computes a 64(o) x 64(n) tile for one tb. K staged in 32-chunks.
// ---------------------------------------------------------------------------
__global__ __launch_bounds__(256) void gemm_f64(
    const float* __restrict__ X, const float* __restrict__ W,
    double* __restrict__ Y)
{
  __shared__ float Wt[64][36];   // [o][cc], padded row (144B, 16B-aligned)
  __shared__ float Xt[32][64];   // [cc][n]
  const int tb = blockIdx.z;
  const int ob = blockIdx.y * 64;
  const int nb = blockIdx.x * 64;
  const int tid = threadIdx.x;
  const int tx = tid & 15;       // n-group: n = nb + 4*tx + j
  const int ty = tid >> 4;       // o-group: o = ob + 4*ty + i

  double acc[4][4];
#pragma unroll
  for (int i = 0; i < 4; ++i)
#pragma unroll
    for (int j = 0; j < 4; ++j) acc[i][j] = 0.0;

  for (int cb = 0; cb < C_; cb += 32) {
    // stage W tile: 64 rows x 32 cols
#pragma unroll
    for (int p = 0; p < 2; ++p) {
      int idx = tid + 256 * p;
      int row = idx >> 3, cq = idx & 7;
      float4 wv = *reinterpret_cast<const float4*>(
          &W[(size_t)(ob + row) * C_ + cb + 4 * cq]);
      *reinterpret_cast<float4*>(&Wt[row][4 * cq]) = wv;
    }
    // stage X tile: 32 rows x 64 cols
#pragma unroll
    for (int p = 0; p < 2; ++p) {
      int idx = tid + 256 * p;
      int row = idx >> 4, nq = idx & 15;
      float4 xv = *reinterpret_cast<const float4*>(
          &X[((size_t)tb * C_ + cb + row) * N_ + nb + 4 * nq]);
      *reinterpret_cast<float4*>(&Xt[row][4 * nq]) = xv;
    }
    __syncthreads();

#pragma unroll
    for (int cq = 0; cq < 32; cq += 4) {
      float4 wf[4], xf[4];
#pragma unroll
      for (int i = 0; i < 4; ++i)
        wf[i] = *reinterpret_cast<const float4*>(&Wt[4 * ty + i][cq]);
#pragma unroll
      for (int q = 0; q < 4; ++q)
        xf[q] = *reinterpret_cast<const float4*>(&Xt[cq + q][4 * tx]);
#pragma unroll
      for (int q = 0; q < 4; ++q) {
        double xd0 = (double)xf[q].x, xd1 = (double)xf[q].y;
        double xd2 = (double)xf[q].z, xd3 = (double)xf[q].w;
#pragma unroll
        for (int i = 0; i < 4; ++i) {
          float wfv = (q == 0) ? wf[i].x : (q == 1) ? wf[i].y
                    : (q == 2) ? wf[i].z : wf[i].w;
          double wd = (double)wfv;
          acc[i][0] = fma(wd, xd0, acc[i][0]);
          acc[i][1] = fma(wd, xd1, acc[i][1]);
          acc[i][2] = fma(wd, xd2, acc[i][2]);
          acc[i][3] = fma(wd, xd3, acc[i][3]);
        }
      }
    }
    __syncthreads();
  }

#pragma unroll
  for (int i = 0; i < 4; ++i) {
    int o = ob + 4 * ty + i;
    double* yp = &Y[((size_t)tb * C_ + o) * N_ + nb + 4 * tx];
#pragma unroll
    for (int j = 0; j < 4; ++j) yp[j] = acc[i][j];
  }
}

// ---------------------------------------------------------------------------
// Per-channel BN statistics over (TB, N) = 16384 values. Deterministic.
// stats[o] = mean, stats[C+o] = 1/sqrt(var + eps)
// ---------------------------------------------------------------------------
__global__ __launch_bounds__(256) void bn_stats(
    const double* __restrict__ Y, double* __restrict__ stats)
{
  const int o = blockIdx.x;
  const int n = threadIdx.x;
  double s = 0.0, s2 = 0.0;
  for (int tb = 0; tb < TB_; ++tb) {
    double v = Y[((size_t)tb * C_ + o) * N_ + n];
    s += v;
    s2 = fma(v, v, s2);
  }
  __shared__ double rs[256], rq[256];
  rs[n] = s; rq[n] = s2;
  __syncthreads();
  for (int off = 128; off > 0; off >>= 1) {
    if (n < off) { rs[n] += rs[n + off]; rq[n] += rq[n + off]; }
    __syncthreads();
  }
  if (n == 0) {
    double mu  = rs[0] * (1.0 / 16384.0);
    double var = rq[0] * (1.0 / 16384.0) - mu * mu;
    stats[o]      = mu;
    stats[C_ + o] = 1.0 / sqrt(var + 1e-5);
  }
}

// ---------------------------------------------------------------------------
// BN-normalize + 4-step LIF (tau=2, hard reset), emit bit-packed spikes.
// One block per (b,o); thread = n. bits layout: [(t*B+b)*C+o][n/64] u64.
// ---------------------------------------------------------------------------
__global__ __launch_bounds__(256) void bn_lif_bits(
    const double* __restrict__ Y, const double* __restrict__ stats,
    const float* __restrict__ gamma, const float* __restrict__ beta,
    double vth, u64* __restrict__ bits)
{
  const int o = blockIdx.x & (C_ - 1);
  const int b = blockIdx.x >> 9;
  const int n = threadIdx.x;
  const double mu = stats[o], rsig = stats[C_ + o];
  const double g = (double)gamma[o], be = (double)beta[o];
  double v = 0.0;
#pragma unroll
  for (int t = 0; t < T_; ++t) {
    double y  = Y[((size_t)(t * B_ + b) * C_ + o) * N_ + n];
    double yn = (y - mu) * rsig * g + be;
    v = v + (yn - v) * 0.5;
    bool sp = (v >= vth);
    u64 m = __ballot(sp);
    if ((n & 63) == 0)
      bits[((size_t)(t * B_ + b) * C_ + o) * (N_ / 64) + (n >> 6)] = m;
    if (sp) v = 0.0;
  }
}

// ---------------------------------------------------------------------------
// Linear attention on binary spikes, exact integer arithmetic.
// Block per (t*B+b, h). kv[dd][e] = popcount over n of (k & v).
// a[n,e] = 0.125 * sum_dd qbit(n,dd) * kv[dd][e], stored at A[c=h*64+e][n].
// ---------------------------------------------------------------------------
__global__ __launch_bounds__(256) void attn_kernel(
    const u64* __restrict__ qb, const u64* __restrict__ kb,
    const u64* __restrict__ vb, float* __restrict__ A)
{
  __shared__ u64 kw[64][4], vw[64][4], qw[64][4];
  __shared__ int kvs[64][64];
  const int h  = blockIdx.x & 7;
  const int tb = blockIdx.x >> 3;
  const int tid = threadIdx.x;
  {
    int dd = tid >> 2, w = tid & 3;
    size_t base = ((size_t)tb * C_ + h * 64 + dd) * 4 + w;
    kw[dd][w] = kb[base];
    vw[dd][w] = vb[base];
    qw[dd][w] = qb[base];
  }
  __syncthreads();
  {
    int dd = tid >> 2;
    int e0 = (tid & 3) << 4;
    u64 k0 = kw[dd][0], k1 = kw[dd][1], k2 = kw[dd][2], k3 = kw[dd][3];
    for (int e = e0; e < e0 + 16; ++e) {
      int c = __popcll(k0 & vw[e][0]) + __popcll(k1 & vw[e][1])
            + __popcll(k2 & vw[e][2]) + __popcll(k3 & vw[e][3]);
      kvs[dd][e] = c;
    }
  }
  __syncthreads();
  const int n = tid;
  u64 qmask = 0;
  {
    int wsel = n >> 6, sh = n & 63;
#pragma unroll
    for (int dd = 0; dd < 64; ++dd)
      qmask |= ((qw[dd][wsel] >> sh) & 1ull) << dd;
  }
  float* Ap = A + ((size_t)tb * C_ + h * 64) * N_ + n;
  for (int e = 0; e < 64; ++e) {
    int s = 0;
#pragma unroll
    for (int dd = 0; dd < 64; ++dd) {
      int m = -(int)((qmask >> dd) & 1ull);
      s += kvs[dd][e] & m;
    }
    Ap[(size_t)e * N_] = (float)s * 0.125f;
  }
}

// ---------------------------------------------------------------------------
// Attention LIF (vth=0.5), exact in fp32 (inputs are multiples of 1/8).
// In-place: A holds a-values, becomes spike {0,1} fp32 (proj GEMM input).
// ---------------------------------------------------------------------------
__global__ __launch_bounds__(256) void attn_lif(float* __restrict__ A)
{
  const size_t i = (size_t)blockIdx.x * 256 + threadIdx.x;  // < B*C*N
  const size_t stride = (size_t)B_ * C_ * N_;
  float v = 0.f;
#pragma unroll
  for (int t = 0; t < T_; ++t) {
    float a = A[t * stride + i];
    v = v + (a - v) * 0.5f;
    bool sp = (v >= 0.5f);
    A[t * stride + i] = sp ? 1.0f : 0.0f;
    if (sp) v = 0.f;
  }
}

// ---------------------------------------------------------------------------
// Final BN + LIF (vth=1.0) writing fp32 spikes to d_out.
// ---------------------------------------------------------------------------
__global__ __launch_bounds__(256) void bn_lif_out(
    const double* __restrict__ Y, const double* __restrict__ stats,
    const float* __restrict__ gamma, const float* __restrict__ beta,
    float* __restrict__ out)
{
  const int o = blockIdx.x & (C_ - 1);
  const int b = blockIdx.x >> 9;
  const int n = threadIdx.x;
  const double mu = stats[o], rsig = stats[C_ + o];
  const double g = (double)gamma[o], be = (double)beta[o];
  double v = 0.0;
#pragma unroll
  for (int t = 0; t < T_; ++t) {
    double y  = Y[((size_t)(t * B_ + b) * C_ + o) * N_ + n];
    double yn = (y - mu) * rsig * g + be;
    v = v + (yn - v) * 0.5;
    bool sp = (v >= 1.0);
    out[((size_t)(t * B_ + b) * C_ + o) * N_ + n] = sp ? 1.0f : 0.0f;
    if (sp) v = 0.0;
  }
}

// ---------------------------------------------------------------------------
extern "C" void kernel_launch(void* const* d_in, const int* in_sizes, int n_in,
                              void* d_out, int out_size, void* d_ws, size_t ws_size,
                              hipStream_t stream)
{
  const float* x    = (const float*)d_in[0];
  const float* qW   = (const float*)d_in[1];
  const float* qg   = (const float*)d_in[2];
  const float* qbt  = (const float*)d_in[3];
  const float* kW   = (const float*)d_in[4];
  const float* kg   = (const float*)d_in[5];
  const float* kbt  = (const float*)d_in[6];
  const float* vW   = (const float*)d_in[7];
  const float* vg   = (const float*)d_in[8];
  const float* vbt  = (const float*)d_in[9];
  const float* pW   = (const float*)d_in[10];
  // d_in[11] proj_b: cancels exactly under BN mean subtraction -> unused
  const float* pg   = (const float*)d_in[12];
  const float* pbt  = (const float*)d_in[13];

  char* ws = (char*)d_ws;
  double* yD    = (double*)ws;                    // 67,108,864 B
  float*  A     = (float*)(ws + 67108864);        // 33,554,432 B
  u64*    bitsQ = (u64*)(ws + 100663296);         //  1,048,576 B
  u64*    bitsK = (u64*)(ws + 101711872);         //  1,048,576 B
  u64*    bitsV = (u64*)(ws + 102760448);         //  1,048,576 B
  double* stats = (double*)(ws + 103809024);      //      8,192 B

  dim3 ggrid(4, 8, 64);  // n-tiles, o-tiles, tb

  // Q branch
  gemm_f64<<<ggrid, 256, 0, stream>>>(x, qW, yD);
  bn_stats<<<512, 256, 0, stream>>>(yD, stats);
  bn_lif_bits<<<8192, 256, 0, stream>>>(yD, stats, qg, qbt, 1.0, bitsQ);
  // K branch
  gemm_f64<<<ggrid, 256, 0, stream>>>(x, kW, yD);
  bn_stats<<<512, 256, 0, stream>>>(yD, stats);
  bn_lif_bits<<<8192, 256, 0, stream>>>(yD, stats, kg, kbt, 1.0, bitsK);
  // V branch
  gemm_f64<<<ggrid, 256, 0, stream>>>(x, vW, yD);
  bn_stats<<<512, 256, 0, stream>>>(yD, stats);
  bn_lif_bits<<<8192, 256, 0, stream>>>(yD, stats, vg, vbt, 1.0, bitsV);
  // attention (exact integer) + attn LIF (exact fp32, in-place -> spikes)
  attn_kernel<<<512, 256, 0, stream>>>(bitsQ, bitsK, bitsV, A);
  attn_lif<<<8192, 256, 0, stream>>>(A);
  // projection
  gemm_f64<<<ggrid, 256, 0, stream>>>(A, pW, yD);
  bn_stats<<<512, 256, 0, stream>>>(yD, stats);
  bn_lif_out<<<8192, 256, 0, stream>>>(yD, stats, pg, pbt, (float*)d_out);
}